// Round 1
// baseline (2042.140 us; speedup 1.0000x reference)
//
#include <hip/hip_runtime.h>
#include <stdint.h>
#include <stddef.h>

typedef int i32x4 __attribute__((ext_vector_type(4)));

// ---------------- workspace layout (bytes) ----------------
#define WS_WFRAG   0          // 262144  w_hh int8, MFMA A-fragment order
#define WS_WIH     262144     // 131072  w_ih int8 [1024][128]
#define WS_BIASHH  393216     // 4096    b_hh_int*256 as i32 [1024]
#define WS_BIASIH  397312     // 4096    b_ih_int*256 as i32 [1024]
#define WS_WLIN    401408     // 1024    w_lin int-valued f32 [256]
#define WS_BLIN    402432     // 4
#define WS_HSTATE  409600     // 16 wg * 8192 = 131072 (h planes, swizzled)
#define WS_CSTATE  540672     // 16*512*8*4 = 262144 (c per lane)
#define WS_GI      1114112    // cs * 524288 bytes (per-step 512 KB)

#define MFMA_I8(a,b,c) __builtin_amdgcn_mfma_i32_16x16x64_i8(a,b,c,0,0,0)

__device__ __forceinline__ float clamp3(float x, float lo, float hi) {
    return __builtin_amdgcn_fmed3f(x, lo, hi);
}
// round-half-even quantize to int16 range, returns integer-valued float (x*256 domain)
__device__ __forceinline__ float q16f(float x) {
    return clamp3(__builtin_rintf(x * 256.0f), -32768.0f, 32767.0f);
}

// ---------------- prep: quantize weights into fragment layouts ----------------
__global__ void prep_kernel(const float* __restrict__ wih, const float* __restrict__ whh,
                            const float* __restrict__ bih, const float* __restrict__ bhh,
                            const float* __restrict__ wlin, const float* __restrict__ blin,
                            uint8_t* __restrict__ ws) {
    int tid = blockIdx.x * blockDim.x + threadIdx.x;   // 262144 threads
    {   // w_hh -> A-fragment order: [wave][mt][kt][lane][16B]
        int p = tid;
        int j = p & 15, lane = (p >> 4) & 63, kt = (p >> 10) & 3, mt = (p >> 12) & 7, w = (p >> 15) & 7;
        int gcol = (mt >> 1) * 256 + w * 32 + (mt & 1) * 16 + (lane & 15);
        int k = kt * 64 + (lane >> 4) * 16 + j;
        int v = (int)q16f(whh[gcol * 256 + k]);
        v = v < -127 ? -127 : (v > 127 ? 127 : v);
        ((int8_t*)(ws + WS_WFRAG))[p] = (int8_t)v;
    }
    if (tid < 131072) {  // w_ih plain [gcol][k] int8
        int gcol = tid >> 7, k = tid & 127;
        int v = (int)q16f(wih[gcol * 128 + k]);
        v = v < -127 ? -127 : (v > 127 ? 127 : v);
        ((int8_t*)(ws + WS_WIH))[tid] = (int8_t)v;
    }
    if (tid < 1024) {    // biases scaled to 2^-16 units (i32)
        ((int*)(ws + WS_BIASHH))[tid] = ((int)q16f(bhh[tid])) * 256;
        ((int*)(ws + WS_BIASIH))[tid] = ((int)q16f(bih[tid])) * 256;
    }
    if (tid < 256) ((float*)(ws + WS_WLIN))[tid] = q16f(wlin[tid]);
    if (tid == 0)  ((float*)(ws + WS_BLIN))[0]   = q16f(blin[0]);
}

// ---------------- gi = quant(xq @ w_ih_q^T + b_ih_q), stored in per-lane slot order ----------
__launch_bounds__(512, 2)
__global__ void gi_kernel(const float* __restrict__ x, uint8_t* __restrict__ ws, int t0) {
    __shared__ uint8_t xa[2048], xb[2048];   // x hi/lo i8 planes [16 rows][128 k], swizzled
    int tid = threadIdx.x;
    int wgr = blockIdx.x;          // batch group 0..15
    int tl  = blockIdx.y;          // chunk-local step
    int t   = t0 + tl;
    {   // stage + quantize + split x
        int row = tid >> 5, c4 = (tid & 31) * 4;
        int b = wgr * 16 + row;
        const float4 xv = *(const float4*)(x + ((size_t)b * 512 + t) * 128 + c4);
        int v0 = (int)q16f(xv.x), v1 = (int)q16f(xv.y), v2 = (int)q16f(xv.z), v3 = (int)q16f(xv.w);
        uint32_t da = ((uint32_t)((v0 >> 7) & 255)) | ((uint32_t)((v1 >> 7) & 255) << 8) |
                      ((uint32_t)((v2 >> 7) & 255) << 16) | ((uint32_t)((v3 >> 7) & 255) << 24);
        uint32_t db = ((uint32_t)(v0 & 127)) | ((uint32_t)(v1 & 127) << 8) |
                      ((uint32_t)(v2 & 127) << 16) | ((uint32_t)(v3 & 127) << 24);
        int addr = row * 128 + (((c4 >> 4) ^ (row & 7)) * 16) + (c4 & 15);
        *(uint32_t*)(xa + addr) = da;
        *(uint32_t*)(xb + addr) = db;
    }
    __syncthreads();
    int wid = tid >> 6, lane = tid & 63, lr = lane & 15, lg = lane >> 4;
    // A fragments (w_ih) straight from global (L2-resident, 64B-line coalesced)
    const uint8_t* wq = ws + WS_WIH;
    i32x4 af[8][2];
#pragma unroll
    for (int mt = 0; mt < 8; ++mt) {
        int gcol = (mt >> 1) * 256 + wid * 32 + (mt & 1) * 16 + lr;
#pragma unroll
        for (int kt = 0; kt < 2; ++kt)
            af[mt][kt] = *(const i32x4*)(wq + gcol * 128 + kt * 64 + lg * 16);
    }
    // B fragments (x planes) from LDS
    i32x4 bha[2], bhb[2];
#pragma unroll
    for (int kt = 0; kt < 2; ++kt) {
        int addr = lr * 128 + ((((kt * 4) + lg) ^ (lr & 7)) * 16);
        bha[kt] = *(const i32x4*)(xa + addr);
        bhb[kt] = *(const i32x4*)(xb + addr);
    }
    i32x4 acch[8], accl[8];
    const int* bi = (const int*)(ws + WS_BIASIH);
#pragma unroll
    for (int mt = 0; mt < 8; ++mt) {
        i32x4 z = {0, 0, 0, 0};
        int gb = (mt >> 1) * 256 + wid * 32 + (mt & 1) * 16 + lg * 4;
        i32x4 bc = *(const i32x4*)(bi + gb);
        acch[mt] = MFMA_I8(af[mt][0], bha[0], z);
        accl[mt] = MFMA_I8(af[mt][0], bhb[0], bc);
        acch[mt] = MFMA_I8(af[mt][1], bha[1], acch[mt]);
        accl[mt] = MFMA_I8(af[mt][1], bhb[1], accl[mt]);
    }
    // combine (x = 128a + b), quantize, pack int16, store in per-lane slot order
    uint8_t* gip = ws + WS_GI + (((size_t)((tl * 16 + wgr) * 8 + wid)) << 12) + lane * 16;
#pragma unroll
    for (int c = 0; c < 4; ++c) {
        i32x4 outv;
#pragma unroll
        for (int d = 0; d < 4; ++d) {
            const int s0 = c * 8 + d * 2, s1 = s0 + 1;
            int v0 = acch[s0 >> 2][s0 & 3] * 128 + accl[s0 >> 2][s0 & 3];
            int v1 = acch[s1 >> 2][s1 & 3] * 128 + accl[s1 >> 2][s1 & 3];
            int g0 = (int)clamp3(__builtin_rintf((float)v0 * 0.00390625f), -32768.0f, 32767.0f);
            int g1 = (int)clamp3(__builtin_rintf((float)v1 * 0.00390625f), -32768.0f, 32767.0f);
            outv[d] = (g0 & 0xFFFF) | (g1 << 16);
        }
        *(i32x4*)(gip + c * 1024) = outv;
    }
}

// ---------------- recurrence: 16 WGs x 16 batch rows, W_hh resident in VGPRs --------------
__launch_bounds__(512, 2)
__global__ void recur_kernel(uint8_t* __restrict__ ws, float* __restrict__ out, int t0, int cs) {
    __shared__ uint8_t hbuf[2][2][4096];   // [dbuf][plane a/b][16 brow][256 k] swizzled
    __shared__ int bias_lds[1024];
    __shared__ float red[512];
    int tid = threadIdx.x, wid = tid >> 6, lane = tid & 63, lr = lane & 15, lg = lane >> 4;
    int wg = blockIdx.x;
    uint8_t* hst = ws + WS_HSTATE + wg * 8192;
    float*   cst = (float*)(ws + WS_CSTATE) + ((size_t)wg * 512 + tid) * 8;

    // W_hh fragments -> registers (persistent across all steps)
    i32x4 wf[8][4];
#pragma unroll
    for (int mt = 0; mt < 8; ++mt)
#pragma unroll
        for (int kt = 0; kt < 4; ++kt)
            wf[mt][kt] = *(const i32x4*)(ws + WS_WFRAG + ((((wid * 8 + mt) * 4 + kt)) << 10) + lane * 16);

    for (int i = tid; i < 1024; i += 512) bias_lds[i] = ((const int*)(ws + WS_BIASHH))[i];

    float c_[8];
    if (t0 == 0) {
#pragma unroll
        for (int i = 0; i < 8; ++i) c_[i] = 0.0f;
        for (int i = tid * 4; i < 8192; i += 2048) *(uint32_t*)(&hbuf[0][0][0] + i) = 0u;
    } else {
#pragma unroll
        for (int i = 0; i < 8; ++i) c_[i] = cst[i];
        for (int i = tid * 4; i < 8192; i += 2048)
            *(uint32_t*)(&hbuf[0][0][0] + i) = *(const uint32_t*)(hst + i);
    }
    __syncthreads();

    int p = 0;
    for (int tl = 0; tl < cs; ++tl) {
        // gi loads (consumed after MFMA phase -> latency hidden)
        const uint8_t* gp = ws + WS_GI + (((size_t)((tl * 16 + wg) * 8 + wid)) << 12) + lane * 16;
        i32x4 g0 = *(const i32x4*)(gp);
        i32x4 g1 = *(const i32x4*)(gp + 1024);
        i32x4 g2 = *(const i32x4*)(gp + 2048);
        i32x4 g3 = *(const i32x4*)(gp + 3072);

        // MFMA phase: gh = h @ W^T (swapped: A=W, B=h^T), h = 4*a + b (i8 planes)
        i32x4 acch[8], accl[8];
#pragma unroll
        for (int kt = 0; kt < 4; ++kt) {
            int baddr = lr * 256 + ((((kt * 4) + lg) ^ lr) * 16);
            i32x4 bh = *(const i32x4*)(&hbuf[p][0][0] + baddr);
            i32x4 bl = *(const i32x4*)(&hbuf[p][1][0] + baddr);
#pragma unroll
            for (int mt = 0; mt < 8; ++mt) {
                if (kt == 0) {
                    i32x4 z = {0, 0, 0, 0};
                    int gb = (mt >> 1) * 256 + wid * 32 + (mt & 1) * 16 + lg * 4;
                    i32x4 bc = *(const i32x4*)(bias_lds + gb);
                    acch[mt] = MFMA_I8(wf[mt][0], bh, z);
                    accl[mt] = MFMA_I8(wf[mt][0], bl, bc);   // bias folded into C
                } else {
                    acch[mt] = MFMA_I8(wf[mt][kt], bh, acch[mt]);
                    accl[mt] = MFMA_I8(wf[mt][kt], bl, accl[mt]);
                }
            }
        }

        // gate phase (all exact fixed-point, round-half-even)
        float iv[8], fv[8], cg[8], ov[8];
#pragma unroll
        for (int mt = 0; mt < 8; ++mt) {
#pragma unroll
            for (int r = 0; r < 4; ++r) {
                const int s = mt * 4 + r;
                int v = acch[mt][r] * 4 + accl[mt][r];   // includes bias*256
                float gh = clamp3(__builtin_rintf((float)v * 0.00390625f), -32768.0f, 32767.0f);
                i32x4 gc = (s >> 3) == 0 ? g0 : ((s >> 3) == 1 ? g1 : ((s >> 3) == 2 ? g2 : g3));
                int hw = gc[(s >> 1) & 3];
                int giv = (s & 1) ? (hw >> 16) : ((hw << 16) >> 16);
                float g = clamp3(gh + (float)giv, -32768.0f, 32767.0f);
                const int gate = mt >> 1;
                const int hs = (mt & 1) * 4 + r;
                if (gate == 2) {
                    cg[hs] = clamp3(g, -256.0f, 256.0f);   // hard_tanh (quant is no-op)
                } else {
                    // quant(hard_sigmoid): rhe((g+768)/6), exact ties via magic div
                    int gi32 = (int)g;
                    gi32 = gi32 < -768 ? -768 : (gi32 > 768 ? 768 : gi32);
                    unsigned u = (unsigned)(gi32 + 768);
                    unsigned q = (u * 43691u) >> 18;           // exact floor(u/6)
                    int rem = (int)u - 6 * (int)q;
                    q += ((rem + (int)(q & 1)) > 3) ? 1u : 0u; // round-half-even
                    float hsv = (float)(int)q;                  // in [0,256]
                    if (gate == 0) iv[hs] = hsv;
                    else if (gate == 1) fv[hs] = hsv;
                    else ov[hs] = hsv;
                }
            }
        }

        // c/h update + pack h into i8 planes
        uint32_t da[2] = {0u, 0u}, db[2] = {0u, 0u};
#pragma unroll
        for (int hs = 0; hs < 8; ++hs) {
            float fc = clamp3(__builtin_rintf(fv[hs] * 0.00390625f * c_[hs]), -32768.0f, 32767.0f);
            float ic = clamp3(__builtin_rintf(iv[hs] * 0.00390625f * cg[hs]), -32768.0f, 32767.0f);
            float cn = clamp3(fc + ic, -32768.0f, 32767.0f);
            c_[hs] = cn;
            float th = clamp3(cn, -256.0f, 256.0f);
            float hv = __builtin_rintf(ov[hs] * 0.00390625f * th);  // |h|<=256, no clamp needed
            int hi = (int)hv;
            const int sub = hs >> 2, rr = hs & 3;
            da[sub] |= (uint32_t)((hi >> 2) & 255) << (8 * rr);
            db[sub] |= (uint32_t)(hi & 3) << (8 * rr);
        }
#pragma unroll
        for (int sub = 0; sub < 2; ++sub) {
            int addr = lr * 256 + (((wid * 2 + sub) ^ lr) * 16) + lg * 4;
            *(uint32_t*)(&hbuf[p ^ 1][0][0] + addr) = da[sub];
            *(uint32_t*)(&hbuf[p ^ 1][1][0] + addr) = db[sub];
        }
        __syncthreads();
        p ^= 1;
    }

    // save state for next chunk
    for (int i = tid * 4; i < 8192; i += 2048)
        *(uint32_t*)(hst + i) = *(const uint32_t*)(&hbuf[p][0][0] + i);
#pragma unroll
    for (int i = 0; i < 8; ++i) cst[i] = c_[i];

    if (t0 + cs == 512) {   // head: out = quant(h_last @ w_lin^T + b_lin)
        int brow = tid & 15, ch = tid >> 4;
        float acc = 0.0f;
        const float* wl = (const float*)(ws + WS_WLIN);
#pragma unroll
        for (int j = 0; j < 8; ++j) {
            int hcol = ch * 8 + j;
            int adr = brow * 256 + (((hcol >> 4) ^ brow) * 16) + (hcol & 15);
            int a = (int)*(const int8_t*)(&hbuf[p][0][0] + adr);
            int b = (int)*(const uint8_t*)(&hbuf[p][1][0] + adr);
            acc += (float)(a * 4 + b) * wl[hcol];
        }
        red[ch * 16 + brow] = acc;
        __syncthreads();
        if (tid < 16) {
            float s = 0.0f;
#pragma unroll
            for (int c2 = 0; c2 < 32; ++c2) s += red[c2 * 16 + tid];
            float bl = ((const float*)(ws + WS_BLIN))[0];
            float o = clamp3(__builtin_rintf(fmaf(s, 0.00390625f, bl)), -32768.0f, 32767.0f);
            out[wg * 16 + tid] = o * 0.00390625f;
        }
    }
}

// ---------------- host ----------------
extern "C" void kernel_launch(void* const* d_in, const int* in_sizes, int n_in,
                              void* d_out, int out_size, void* d_ws, size_t ws_size,
                              hipStream_t stream) {
    const float* x    = (const float*)d_in[0];
    const float* wih  = (const float*)d_in[1];
    const float* whh  = (const float*)d_in[2];
    const float* bih  = (const float*)d_in[3];
    const float* bhh  = (const float*)d_in[4];
    const float* wlin = (const float*)d_in[5];
    const float* blin = (const float*)d_in[6];
    float* out = (float*)d_out;
    uint8_t* ws = (uint8_t*)d_ws;

    prep_kernel<<<512, 512, 0, stream>>>(wih, whh, bih, bhh, wlin, blin, ws);

    int cs = 512;
    while ((size_t)WS_GI + (size_t)cs * 524288 > ws_size && cs > 8) cs >>= 1;

    for (int t0 = 0; t0 < 512; t0 += cs) {
        gi_kernel<<<dim3(16, cs), 512, 0, stream>>>(x, ws, t0);
        recur_kernel<<<16, 512, 0, stream>>>(ws, out, t0, cs);
    }
}

// Round 3
// 793.323 us; speedup vs baseline: 2.5742x; 2.5742x over previous
//
#include <hip/hip_runtime.h>
#include <stdint.h>
#include <stddef.h>

typedef int i32x4 __attribute__((ext_vector_type(4)));

// ---------------- workspace layout (bytes) ----------------
#define WS_WFRAG   0u          // 262144  w_hh int8, [w8][t8][ks4][lane64][16]
#define WS_WIH     262144u     // 131072  w_ih int8 [1024][128]
#define WS_BIASHH  393216u     // 4096    b_hh_int*256 as i32 [1024]
#define WS_BIASIH  397312u     // 4096    b_ih_int*256 as i32 [1024]
#define WS_WLIN    401408u     // 1024    w_lin int i32 [256]
#define WS_BLIN    402432u     // 4       b_lin int
#define WS_HSTATE  409600u     // 64 wg * 2048 = 131072 (h planes, swizzled)
#define WS_CSTATE  540672u     // 64*512*2*4 = 262144 (c per lane, 2 each)
#define WS_GI      1048576u    // cs * 524288 bytes (chunk-local step ring)

#define MFMA_I8(a,b,c) __builtin_amdgcn_mfma_i32_16x16x64_i8(a,b,c,0,0,0)
#define RHE8(x) ((((x) + 127) + (((x) >> 8) & 1)) >> 8)

__device__ __forceinline__ float clamp3(float x, float lo, float hi) {
    return __builtin_amdgcn_fmed3f(x, lo, hi);
}
__device__ __forceinline__ float q16f(float x) {
    return clamp3(__builtin_rintf(x * 256.0f), -32768.0f, 32767.0f);
}
__device__ __forceinline__ int iclamp(int v, int lo, int hi) {
    return v < lo ? lo : (v > hi ? hi : v);
}

// ---------------- prep: quantize weights into fragment layouts ----------------
__global__ void prep_kernel(const float* __restrict__ wih, const float* __restrict__ whh,
                            const float* __restrict__ bih, const float* __restrict__ bhh,
                            const float* __restrict__ wlin, const float* __restrict__ blin,
                            uint8_t* __restrict__ ws) {
    int tid = blockIdx.x * blockDim.x + threadIdx.x;   // 262144 threads
    {   // w_hh -> A-fragment order: [w][t8][ks][lane][16B]
        int p = tid;
        int j = p & 15, lane = (p >> 4) & 63, ks = (p >> 10) & 3, t8 = (p >> 12) & 7, w = (p >> 15) & 7;
        int row = (t8 >> 1) * 256 + w * 32 + (t8 & 1) * 16 + (lane & 15);
        int k = ks * 64 + (lane >> 4) * 16 + j;
        int v = (int)q16f(whh[row * 256 + k]);
        v = iclamp(v, -127, 127);
        ((int8_t*)(ws + WS_WFRAG))[p] = (int8_t)v;
    }
    if (tid < 131072) {  // w_ih plain [gcol][k] int8
        int gcol = tid >> 7, k = tid & 127;
        int v = (int)q16f(wih[gcol * 128 + k]);
        v = iclamp(v, -127, 127);
        ((int8_t*)(ws + WS_WIH))[tid] = (int8_t)v;
    }
    if (tid < 1024) {    // biases scaled to 2^-16 units (i32)
        ((int*)(ws + WS_BIASHH))[tid] = ((int)q16f(bhh[tid])) * 256;
        ((int*)(ws + WS_BIASIH))[tid] = ((int)q16f(bih[tid])) * 256;
    }
    if (tid < 256) ((int*)(ws + WS_WLIN))[tid] = (int)q16f(wlin[tid]);
    if (tid == 0)  ((int*)(ws + WS_BLIN))[0]   = (int)q16f(blin[0]);
}

// ---------------- gi = quant(xq @ w_ih_q^T + b_ih_q), stored per-lane slot order ----------
__launch_bounds__(512, 2)
__global__ void gi_kernel(const float* __restrict__ x, uint8_t* __restrict__ ws, int t0) {
    __shared__ uint8_t xa[2048], xb[2048];   // x hi/lo i8 planes [16 rows][128 k], swizzled
    int tid = threadIdx.x;
    int wgr = blockIdx.x;          // batch group of 16, 0..15
    int tl  = blockIdx.y;          // chunk-local step  (ring index!)
    int t   = t0 + tl;             // global step (x read only)
    {   // stage + quantize + split x (x = 128a + b)
        int row = tid >> 5, c4 = (tid & 31) * 4;
        int b = wgr * 16 + row;
        const float4 xv = *(const float4*)(x + ((size_t)b * 512 + t) * 128 + c4);
        int v0 = (int)q16f(xv.x), v1 = (int)q16f(xv.y), v2 = (int)q16f(xv.z), v3 = (int)q16f(xv.w);
        uint32_t da = ((uint32_t)((v0 >> 7) & 255)) | ((uint32_t)((v1 >> 7) & 255) << 8) |
                      ((uint32_t)((v2 >> 7) & 255) << 16) | ((uint32_t)((v3 >> 7) & 255) << 24);
        uint32_t db = ((uint32_t)(v0 & 127)) | ((uint32_t)(v1 & 127) << 8) |
                      ((uint32_t)(v2 & 127) << 16) | ((uint32_t)(v3 & 127) << 24);
        int addr = row * 128 + (((c4 >> 4) ^ (row & 7)) * 16) + (c4 & 15);
        *(uint32_t*)(xa + addr) = da;
        *(uint32_t*)(xb + addr) = db;
    }
    __syncthreads();
    int wid = tid >> 6, lane = tid & 63, lr = lane & 15, lg = lane >> 4;
    const uint8_t* wq = ws + WS_WIH;
    i32x4 af[8][2];
#pragma unroll
    for (int mt = 0; mt < 8; ++mt) {
        int gcol = (mt >> 1) * 256 + wid * 32 + (mt & 1) * 16 + lr;
#pragma unroll
        for (int kt = 0; kt < 2; ++kt)
            af[mt][kt] = *(const i32x4*)(wq + gcol * 128 + kt * 64 + lg * 16);
    }
    i32x4 bha[2], bhb[2];
#pragma unroll
    for (int kt = 0; kt < 2; ++kt) {
        int addr = lr * 128 + ((((kt * 4) + lg) ^ (lr & 7)) * 16);
        bha[kt] = *(const i32x4*)(xa + addr);
        bhb[kt] = *(const i32x4*)(xb + addr);
    }
    i32x4 acch[8], accl[8];
    const int* bi = (const int*)(ws + WS_BIASIH);
#pragma unroll
    for (int mt = 0; mt < 8; ++mt) {
        i32x4 z = {0, 0, 0, 0};
        int gb = (mt >> 1) * 256 + wid * 32 + (mt & 1) * 16 + lg * 4;
        i32x4 bc = *(const i32x4*)(bi + gb);
        acch[mt] = MFMA_I8(af[mt][0], bha[0], z);
        accl[mt] = MFMA_I8(af[mt][0], bhb[0], bc);   // bias folded into C (enters v once)
        acch[mt] = MFMA_I8(af[mt][1], bha[1], acch[mt]);
        accl[mt] = MFMA_I8(af[mt][1], bhb[1], accl[mt]);
    }
    // quantize (exact RHE) and scatter into recur's per-lane slot order
    int gq[8][4];
#pragma unroll
    for (int mt = 0; mt < 8; ++mt)
#pragma unroll
        for (int rr = 0; rr < 4; ++rr) {
            int v = acch[mt][rr] * 128 + accl[mt][rr];
            gq[mt][rr] = iclamp(RHE8(v), -32768, 32767);
        }
    unsigned wbv = (unsigned)(wgr * 4 + (lr >> 2));   // dest WG (4-batch group)
#pragma unroll
    for (int mv = 0; mv < 2; ++mv)
#pragma unroll
        for (int pqv = 0; pqv < 2; ++pqv) {
            i32x4 outv;
#pragma unroll
            for (int G = 0; G < 4; ++G)
                outv[G] = (gq[2 * G + mv][pqv] & 0xFFFF) | (gq[2 * G + mv][pqv + 2] << 16);
            int L = (lane & 3) + 4 * pqv + 8 * mv + 16 * (lane >> 4);
            *(i32x4*)(ws + WS_GI + (size_t)tl * 524288u +
                      (size_t)(((wbv * 8u + (unsigned)wid) * 64u) + (unsigned)L) * 16u) = outv;
        }
}

// ---------------- recurrence: 64 WGs x 4 batch rows, W_hh resident in VGPRs --------------
__launch_bounds__(512, 2)
__global__ void recur_kernel(uint8_t* __restrict__ ws, float* __restrict__ out, int t0, int cs) {
    __shared__ __align__(16) uint8_t hbuf[2][2048];   // [dbuf][p(2)][b(4)][k(256)] swizzled
    __shared__ unsigned short lut[1544];              // quant(hard_sigmoid) LUT, u in [0,1536]
    __shared__ long long redl[8][4];
    int tid = threadIdx.x, w = tid >> 6, lane = tid & 63;
    int wb = blockIdx.x;
    int b   = lane & 3;
    int pq  = (lane >> 2) & 1;
    int m   = (lane >> 3) & 1;
    int sg  = lane >> 4;           // 0..3
    int col = lane & 15;
    int cb  = col & 3;             // B-frag col batch (cols 8-15 mirror)
    int cp  = (col >> 2) & 1;      // B-frag col plane
    uint8_t* hb0 = &hbuf[0][0];

    // sigmoid LUT built with the EXACT fp64 expression the np reference evaluates:
    // y = (n/256)/6 + 0.5, clip01, rint(y*256)  (matches tie-resolution bit-for-bit)
    for (int u = tid; u < 1537; u += 512) {
        double y = ((double)(u - 768) / 256.0) / 6.0 + 0.5;
        y = y < 0.0 ? 0.0 : (y > 1.0 ? 1.0 : y);
        lut[u] = (unsigned short)(int)__builtin_rint(y * 256.0);
    }

    // W_hh fragments -> registers (persistent across all steps)
    i32x4 wf[8][4];
#pragma unroll
    for (int t8 = 0; t8 < 8; ++t8)
#pragma unroll
        for (int ks = 0; ks < 4; ++ks)
            wf[t8][ks] = *(const i32x4*)(ws + WS_WFRAG + (((unsigned)(w * 8 + t8) * 4 + ks) << 10) + lane * 16);

    // static per-lane addresses
    int addrB[4];
#pragma unroll
    for (int ks = 0; ks < 4; ++ks) {
        int swz = (2 * cb + cp) & 7;
        addrB[ks] = cp * 1024 + cb * 256 + ((ks * 64 + sg * 16) ^ (swz << 4));
    }
    int addrWa[2], addrWb[2], biasv[4][2], wlv[2];
    const int* bhh256 = (const int*)(ws + WS_BIASHH);
    const int* wlin_i = (const int*)(ws + WS_WLIN);
#pragma unroll
    for (int e = 0; e < 2; ++e) {
        int hl = 16 * m + 4 * sg + 2 * e + pq;
        int k  = w * 32 + hl;
        int swa = (2 * b + 0) & 7, swb = (2 * b + 1) & 7;
        addrWa[e] = 0 * 1024 + b * 256 + (k ^ (swa << 4));
        addrWb[e] = 1 * 1024 + b * 256 + (k ^ (swb << 4));
#pragma unroll
        for (int G = 0; G < 4; ++G) biasv[G][e] = bhh256[G * 256 + k];
        wlv[e] = wlin_i[k];
    }
    size_t gioff = (size_t)(((unsigned)wb * 8u + (unsigned)w) * 64u + (unsigned)lane) * 16u;

    uint8_t* hst = ws + WS_HSTATE + (unsigned)wb * 2048u;
    int* cst = (int*)(ws + WS_CSTATE) + ((unsigned)wb * 512u + (unsigned)tid) * 2;

    int c_[2];
    if (t0 == 0) {
        c_[0] = 0; c_[1] = 0;
        *(uint32_t*)(hb0 + tid * 4) = 0u;
    } else {
        c_[0] = cst[0]; c_[1] = cst[1];
        *(uint32_t*)(hb0 + tid * 4) = *(const uint32_t*)(hst + tid * 4);
    }
    __syncthreads();

    int hl0_ = 0, hl1_ = 0;
    const i32x4 zerov = {0, 0, 0, 0};

#define STEP(PP, TLIDX)                                                                \
    {                                                                                  \
        i32x4 gvec = *(const i32x4*)(ws + WS_GI + (size_t)(TLIDX) * 524288u + gioff);  \
        i32x4 acc[8];                                                                  \
        _Pragma("unroll")                                                              \
        for (int ks = 0; ks < 4; ++ks) {                                               \
            i32x4 bf = *(const i32x4*)(hb0 + (PP) * 2048 + addrB[ks]);                 \
            _Pragma("unroll")                                                          \
            for (int t8 = 0; t8 < 8; ++t8)                                             \
                acc[t8] = (ks == 0) ? MFMA_I8(wf[t8][0], bf, zerov)                    \
                                    : MFMA_I8(wf[t8][ks], bf, acc[t8]);                \
        }                                                                              \
        _Pragma("unroll")                                                              \
        for (int e = 0; e < 2; ++e) {                                                  \
            int gate0, gate1, gate2, gate3;                                            \
            _Pragma("unroll")                                                          \
            for (int G = 0; G < 4; ++G) {                                              \
                int rA0 = acc[2 * G][2 * e],     rB0 = acc[2 * G][2 * e + 1];          \
                int rA1 = acc[2 * G + 1][2 * e], rB1 = acc[2 * G + 1][2 * e + 1];      \
                int z10 = __builtin_amdgcn_ds_swizzle(rA0, 0x101F);                    \
                int z20 = __builtin_amdgcn_ds_swizzle(rB0, 0x101F);                    \
                int z11 = __builtin_amdgcn_ds_swizzle(rA1, 0x101F);                    \
                int z21 = __builtin_amdgcn_ds_swizzle(rB1, 0x101F);                    \
                int c0 = pq ? ((z20 << 2) + rB0) : ((rA0 << 2) + z10);                 \
                int c1 = pq ? ((z21 << 2) + rB1) : ((rA1 << 2) + z11);                 \
                int d  = m ? c1 : c0;                                                  \
                int v  = d + biasv[G][e];                                              \
                int gh = RHE8(v);                                                      \
                int giv = (e == 0) ? ((gvec[G] << 16) >> 16) : (gvec[G] >> 16);        \
                int g = gh + giv;                                                      \
                if (G == 2) {                                                          \
                    gate2 = iclamp(g, -256, 256);                                      \
                } else {                                                               \
                    int idx = iclamp(g, -768, 768) + 768;                              \
                    int sv = (int)lut[idx];                                            \
                    if (G == 0) gate0 = sv; else if (G == 1) gate1 = sv; else gate3 = sv; \
                }                                                                      \
            }                                                                          \
            int cc  = c_[e];                                                           \
            int fcq = RHE8(__mul24(gate1, cc));                                        \
            int icq = RHE8(__mul24(gate0, gate2));                                     \
            int cn  = iclamp(fcq + icq, -32768, 32767);                                \
            c_[e] = cn;                                                                \
            int th = iclamp(cn, -256, 256);                                            \
            int hq = RHE8(__mul24(gate3, th));                                         \
            *(int8_t*)(hb0 + ((PP) ^ 1) * 2048 + addrWa[e]) = (int8_t)(hq >> 2);       \
            *(int8_t*)(hb0 + ((PP) ^ 1) * 2048 + addrWb[e]) = (int8_t)(hq & 3);        \
            if (e == 0) hl0_ = hq; else hl1_ = hq;                                     \
        }                                                                              \
        __syncthreads();                                                               \
    }

    for (int tl = 0; tl < cs; tl += 2) {
        STEP(0, tl)
        STEP(1, tl + 1)
    }
#undef STEP

    // save state for next chunk (final buffer parity is 0 since cs is even)
    *(uint32_t*)(hst + tid * 4) = *(const uint32_t*)(hb0 + tid * 4);
    cst[0] = c_[0]; cst[1] = c_[1];

    if (t0 + cs == 512) {   // head: out = quant(h_last @ w_lin^T + b_lin), exact int64
        long long s = (long long)hl0_ * (long long)wlv[0] + (long long)hl1_ * (long long)wlv[1];
        s += __shfl_xor(s, 4);
        s += __shfl_xor(s, 8);
        s += __shfl_xor(s, 16);
        s += __shfl_xor(s, 32);
        if (lane < 4) redl[w][lane] = s;
        __syncthreads();
        if (tid < 4) {
            long long tot = 0;
#pragma unroll
            for (int ww = 0; ww < 8; ++ww) tot += redl[ww][tid];
            tot += 256LL * (long long)((const int*)(ws + WS_BLIN))[0];
            long long q = ((tot + 127) + ((tot >> 8) & 1)) >> 8;
            q = q < -32768 ? -32768 : (q > 32767 ? 32767 : q);
            out[wb * 4 + tid] = (float)q * 0.00390625f;
        }
    }
}

// ---------------- host ----------------
extern "C" void kernel_launch(void* const* d_in, const int* in_sizes, int n_in,
                              void* d_out, int out_size, void* d_ws, size_t ws_size,
                              hipStream_t stream) {
    const float* x    = (const float*)d_in[0];
    const float* wih  = (const float*)d_in[1];
    const float* whh  = (const float*)d_in[2];
    const float* bih  = (const float*)d_in[3];
    const float* bhh  = (const float*)d_in[4];
    const float* wlin = (const float*)d_in[5];
    const float* blin = (const float*)d_in[6];
    float* out = (float*)d_out;
    uint8_t* ws = (uint8_t*)d_ws;

    prep_kernel<<<512, 512, 0, stream>>>(wih, whh, bih, bhh, wlin, blin, ws);

    int cs = 512;
    while ((size_t)WS_GI + (size_t)cs * 524288u > ws_size && cs > 8) cs >>= 1;

    for (int t0 = 0; t0 < 512; t0 += cs) {
        gi_kernel<<<dim3(16, cs), 512, 0, stream>>>(x, ws, t0);
        recur_kernel<<<64, 512, 0, stream>>>(ws, out, t0, cs);
    }
}

// Round 4
// 691.517 us; speedup vs baseline: 2.9531x; 1.1472x over previous
//
#include <hip/hip_runtime.h>
#include <stdint.h>
#include <stddef.h>

typedef int i32x4 __attribute__((ext_vector_type(4)));

// ---------------- workspace layout (bytes) ----------------
#define WS_WFRAG   0u          // 262144  w_hh int8, [w8][t8][ks4][lane64][16]
#define WS_WIH     262144u     // 131072  w_ih int8 [1024][128]
#define WS_BIASHH  393216u     // 4096    b_hh_int*256 as i32 [1024]
#define WS_BIASIH  397312u     // 4096    b_ih_int*256 as i32 [1024]
#define WS_WLIN    401408u     // 1024    w_lin int i32 [256]
#define WS_BLIN    402432u     // 4       b_lin int
#define WS_HSTATE  409600u     // 64 wg * 2048 = 131072 (h planes, swizzled)
#define WS_CSTATE  540672u     // 64*512*2*4 = 262144 (c per lane, 2 each)
#define WS_GI      1048576u    // cs * 524288 bytes (chunk-local step ring)

#define MFMA_I8(a,b,c) __builtin_amdgcn_mfma_i32_16x16x64_i8(a,b,c,0,0,0)
#define RHE8(x) ((((x) + 127) + (((x) >> 8) & 1)) >> 8)

// LDS-drain-only barrier: keeps global prefetch loads in flight across steps
// (plain __syncthreads would emit s_waitcnt vmcnt(0) and kill the prefetch).
#define BAR() do { asm volatile("s_waitcnt lgkmcnt(0)" ::: "memory"); \
                   __builtin_amdgcn_s_barrier(); } while (0)

__device__ __forceinline__ float clamp3(float x, float lo, float hi) {
    return __builtin_amdgcn_fmed3f(x, lo, hi);
}
__device__ __forceinline__ float q16f(float x) {
    return clamp3(__builtin_rintf(x * 256.0f), -32768.0f, 32767.0f);
}
__device__ __forceinline__ int iclamp(int v, int lo, int hi) {
    return v < lo ? lo : (v > hi ? hi : v);
}

// ---------------- prep: quantize weights into fragment layouts ----------------
__global__ void prep_kernel(const float* __restrict__ wih, const float* __restrict__ whh,
                            const float* __restrict__ bih, const float* __restrict__ bhh,
                            const float* __restrict__ wlin, const float* __restrict__ blin,
                            uint8_t* __restrict__ ws) {
    int tid = blockIdx.x * blockDim.x + threadIdx.x;   // 262144 threads
    {   // w_hh -> A-fragment order: [w][t8][ks][lane][16B]
        int p = tid;
        int j = p & 15, lane = (p >> 4) & 63, ks = (p >> 10) & 3, t8 = (p >> 12) & 7, w = (p >> 15) & 7;
        int row = (t8 >> 1) * 256 + w * 32 + (t8 & 1) * 16 + (lane & 15);
        int k = ks * 64 + (lane >> 4) * 16 + j;
        int v = (int)q16f(whh[row * 256 + k]);
        v = iclamp(v, -127, 127);
        ((int8_t*)(ws + WS_WFRAG))[p] = (int8_t)v;
    }
    if (tid < 131072) {  // w_ih plain [gcol][k] int8
        int gcol = tid >> 7, k = tid & 127;
        int v = (int)q16f(wih[gcol * 128 + k]);
        v = iclamp(v, -127, 127);
        ((int8_t*)(ws + WS_WIH))[tid] = (int8_t)v;
    }
    if (tid < 1024) {    // biases scaled to 2^-16 units (i32)
        ((int*)(ws + WS_BIASHH))[tid] = ((int)q16f(bhh[tid])) * 256;
        ((int*)(ws + WS_BIASIH))[tid] = ((int)q16f(bih[tid])) * 256;
    }
    if (tid < 256) ((int*)(ws + WS_WLIN))[tid] = (int)q16f(wlin[tid]);
    if (tid == 0)  ((int*)(ws + WS_BLIN))[0]   = (int)q16f(blin[0]);
}

// ---------------- gi = quant(xq @ w_ih_q^T + b_ih_q), stored per-lane slot order ----------
__launch_bounds__(512, 2)
__global__ void gi_kernel(const float* __restrict__ x, uint8_t* __restrict__ ws, int t0) {
    __shared__ uint8_t xa[2048], xb[2048];   // x hi/lo i8 planes [16 rows][128 k], swizzled
    int tid = threadIdx.x;
    int wgr = blockIdx.x;          // batch group of 16, 0..15
    int tl  = blockIdx.y;          // chunk-local step  (ring index!)
    int t   = t0 + tl;             // global step (x read only)
    {   // stage + quantize + split x (x = 128a + b)
        int row = tid >> 5, c4 = (tid & 31) * 4;
        int b = wgr * 16 + row;
        const float4 xv = *(const float4*)(x + ((size_t)b * 512 + t) * 128 + c4);
        int v0 = (int)q16f(xv.x), v1 = (int)q16f(xv.y), v2 = (int)q16f(xv.z), v3 = (int)q16f(xv.w);
        uint32_t da = ((uint32_t)((v0 >> 7) & 255)) | ((uint32_t)((v1 >> 7) & 255) << 8) |
                      ((uint32_t)((v2 >> 7) & 255) << 16) | ((uint32_t)((v3 >> 7) & 255) << 24);
        uint32_t db = ((uint32_t)(v0 & 127)) | ((uint32_t)(v1 & 127) << 8) |
                      ((uint32_t)(v2 & 127) << 16) | ((uint32_t)(v3 & 127) << 24);
        int addr = row * 128 + (((c4 >> 4) ^ (row & 7)) * 16) + (c4 & 15);
        *(uint32_t*)(xa + addr) = da;
        *(uint32_t*)(xb + addr) = db;
    }
    __syncthreads();
    int wid = tid >> 6, lane = tid & 63, lr = lane & 15, lg = lane >> 4;
    const uint8_t* wq = ws + WS_WIH;
    i32x4 af[8][2];
#pragma unroll
    for (int mt = 0; mt < 8; ++mt) {
        int gcol = (mt >> 1) * 256 + wid * 32 + (mt & 1) * 16 + lr;
#pragma unroll
        for (int kt = 0; kt < 2; ++kt)
            af[mt][kt] = *(const i32x4*)(wq + gcol * 128 + kt * 64 + lg * 16);
    }
    i32x4 bha[2], bhb[2];
#pragma unroll
    for (int kt = 0; kt < 2; ++kt) {
        int addr = lr * 128 + ((((kt * 4) + lg) ^ (lr & 7)) * 16);
        bha[kt] = *(const i32x4*)(xa + addr);
        bhb[kt] = *(const i32x4*)(xb + addr);
    }
    i32x4 acch[8], accl[8];
    const int* bi = (const int*)(ws + WS_BIASIH);
#pragma unroll
    for (int mt = 0; mt < 8; ++mt) {
        i32x4 z = {0, 0, 0, 0};
        int gb = (mt >> 1) * 256 + wid * 32 + (mt & 1) * 16 + lg * 4;
        i32x4 bc = *(const i32x4*)(bi + gb);
        acch[mt] = MFMA_I8(af[mt][0], bha[0], z);
        accl[mt] = MFMA_I8(af[mt][0], bhb[0], bc);   // bias folded into C (enters v once)
        acch[mt] = MFMA_I8(af[mt][1], bha[1], acch[mt]);
        accl[mt] = MFMA_I8(af[mt][1], bhb[1], accl[mt]);
    }
    // quantize (exact RHE) and scatter into recur's per-lane slot order
    int gq[8][4];
#pragma unroll
    for (int mt = 0; mt < 8; ++mt)
#pragma unroll
        for (int rr = 0; rr < 4; ++rr) {
            int v = acch[mt][rr] * 128 + accl[mt][rr];
            gq[mt][rr] = iclamp(RHE8(v), -32768, 32767);
        }
    unsigned wbv = (unsigned)(wgr * 4 + (lr >> 2));   // dest WG (4-batch group)
#pragma unroll
    for (int mv = 0; mv < 2; ++mv)
#pragma unroll
        for (int pqv = 0; pqv < 2; ++pqv) {
            i32x4 outv;
#pragma unroll
            for (int G = 0; G < 4; ++G)
                outv[G] = (gq[2 * G + mv][pqv] & 0xFFFF) | (gq[2 * G + mv][pqv + 2] << 16);
            int L = (lane & 3) + 4 * pqv + 8 * mv + 16 * (lane >> 4);
            *(i32x4*)(ws + WS_GI + (size_t)tl * 524288u +
                      (size_t)(((wbv * 8u + (unsigned)wid) * 64u) + (unsigned)L) * 16u) = outv;
        }
}

// ---------------- recurrence: 64 WGs x 4 batch rows, W_hh resident in VGPRs --------------
__launch_bounds__(512, 2)
__global__ void recur_kernel(uint8_t* __restrict__ ws, float* __restrict__ out, int t0, int cs) {
    __shared__ __align__(16) uint8_t hbuf[2][2048];   // [dbuf][p(2)][b(4)][k(256)] swizzled
    __shared__ unsigned short lut[1544];              // quant(hard_sigmoid) LUT, u in [0,1536]
    __shared__ long long redl[8][4];
    int tid = threadIdx.x, w = tid >> 6, lane = tid & 63;
    int wb = blockIdx.x;
    int b   = lane & 3;
    int pq  = (lane >> 2) & 1;
    int m   = (lane >> 3) & 1;
    int sg  = lane >> 4;           // 0..3
    int col = lane & 15;
    int cb  = col & 3;             // B-frag col batch (cols 8-15 mirror)
    int cp  = (col >> 2) & 1;      // B-frag col plane
    uint8_t* hb0 = &hbuf[0][0];

    // sigmoid LUT built with the EXACT fp64 expression the np reference evaluates:
    // y = (n/256)/6 + 0.5, clip01, rint(y*256)
    for (int u = tid; u < 1537; u += 512) {
        double y = ((double)(u - 768) / 256.0) / 6.0 + 0.5;
        y = y < 0.0 ? 0.0 : (y > 1.0 ? 1.0 : y);
        lut[u] = (unsigned short)(int)__builtin_rint(y * 256.0);
    }

    // W_hh fragments -> registers (persistent across all steps)
    i32x4 wf[8][4];
#pragma unroll
    for (int t8 = 0; t8 < 8; ++t8)
#pragma unroll
        for (int ks = 0; ks < 4; ++ks)
            wf[t8][ks] = *(const i32x4*)(ws + WS_WFRAG + (((unsigned)(w * 8 + t8) * 4 + ks) << 10) + lane * 16);

    // static per-lane addresses
    int addrB[4];
#pragma unroll
    for (int ks = 0; ks < 4; ++ks) {
        int swz = (2 * cb + cp) & 7;
        addrB[ks] = cp * 1024 + cb * 256 + ((ks * 64 + sg * 16) ^ (swz << 4));
    }
    int addrWa[2], addrWb[2], biasv[4][2], wlv[2];
    const int* bhh256 = (const int*)(ws + WS_BIASHH);
    const int* wlin_i = (const int*)(ws + WS_WLIN);
#pragma unroll
    for (int e = 0; e < 2; ++e) {
        int hl = 16 * m + 4 * sg + 2 * e + pq;
        int k  = w * 32 + hl;
        int swa = (2 * b + 0) & 7, swb = (2 * b + 1) & 7;
        addrWa[e] = 0 * 1024 + b * 256 + (k ^ (swa << 4));
        addrWb[e] = 1 * 1024 + b * 256 + (k ^ (swb << 4));
#pragma unroll
        for (int G = 0; G < 4; ++G) biasv[G][e] = bhh256[G * 256 + k];
        wlv[e] = wlin_i[k];
    }
    size_t gioff = (size_t)(((unsigned)wb * 8u + (unsigned)w) * 64u + (unsigned)lane) * 16u;

    uint8_t* hst = ws + WS_HSTATE + (unsigned)wb * 2048u;
    int* cst = (int*)(ws + WS_CSTATE) + ((unsigned)wb * 512u + (unsigned)tid) * 2;

    int c_[2];
    if (t0 == 0) {
        c_[0] = 0; c_[1] = 0;
        *(uint32_t*)(hb0 + tid * 4) = 0u;
    } else {
        c_[0] = cst[0]; c_[1] = cst[1];
        *(uint32_t*)(hb0 + tid * 4) = *(const uint32_t*)(hst + tid * 4);
    }
    // prefetch gi for step 0 (stays in VGPRs across the barrier)
    i32x4 gcur = *(const i32x4*)(ws + WS_GI + gioff);
    i32x4 gnx;
    __syncthreads();

    int hl0_ = 0, hl1_ = 0;
    const i32x4 zerov = {0, 0, 0, 0};

    // STEP: uses GUSE (prefetched last step), prefetches step TPRE into GPRE.
    // Cross-lane combine: partner = lane^4 (flips pq, keeps m/b/sg).
    //   pq=0 lane owns hi-plane accs, needs partner's lo (A-row slot);
    //   pq=1 lane owns lo-plane accs, needs partner's hi (B-row slot).
    //   Each sends rX = pq ? rA : rB  ->  1 ds_swizzle per (e,G).
#define STEP(PP, GUSE, GPRE, TPRE)                                                     \
    {                                                                                  \
        GPRE = *(const i32x4*)(ws + WS_GI + (size_t)(TPRE) * 524288u + gioff);         \
        i32x4 acc[8];                                                                  \
        _Pragma("unroll")                                                              \
        for (int ks = 0; ks < 4; ++ks) {                                               \
            i32x4 bf = *(const i32x4*)(hb0 + (PP) * 2048 + addrB[ks]);                 \
            _Pragma("unroll")                                                          \
            for (int t8 = 0; t8 < 8; ++t8)                                             \
                acc[t8] = (ks == 0) ? MFMA_I8(wf[t8][0], bf, zerov)                    \
                                    : MFMA_I8(wf[t8][ks], bf, acc[t8]);                \
        }                                                                              \
        _Pragma("unroll")                                                              \
        for (int e = 0; e < 2; ++e) {                                                  \
            int gate0, gate1, gate2, gate3;                                            \
            _Pragma("unroll")                                                          \
            for (int G = 0; G < 4; ++G) {                                              \
                int rA = m ? acc[2 * G + 1][2 * e]     : acc[2 * G][2 * e];            \
                int rB = m ? acc[2 * G + 1][2 * e + 1] : acc[2 * G][2 * e + 1];        \
                int rX = pq ? rA : rB;                                                 \
                int zX = __builtin_amdgcn_ds_swizzle(rX, 0x101F);                      \
                int d  = pq ? ((zX << 2) + rB) : ((rA << 2) + zX);                     \
                int v  = d + biasv[G][e];                                              \
                int gh = RHE8(v);                                                      \
                int giv = (e == 0) ? ((GUSE[G] << 16) >> 16) : (GUSE[G] >> 16);        \
                int g = gh + giv;                                                      \
                if (G == 2) {                                                          \
                    gate2 = iclamp(g, -256, 256);                                      \
                } else {                                                               \
                    int idx = iclamp(g, -768, 768) + 768;                              \
                    int sv = (int)lut[idx];                                            \
                    if (G == 0) gate0 = sv; else if (G == 1) gate1 = sv; else gate3 = sv; \
                }                                                                      \
            }                                                                          \
            int cc  = c_[e];                                                           \
            int fcq = RHE8(__mul24(gate1, cc));                                        \
            int icq = RHE8(__mul24(gate0, gate2));                                     \
            int cn  = iclamp(fcq + icq, -32768, 32767);                                \
            c_[e] = cn;                                                                \
            int th = iclamp(cn, -256, 256);                                            \
            int hq = RHE8(__mul24(gate3, th));                                         \
            *(int8_t*)(hb0 + ((PP) ^ 1) * 2048 + addrWa[e]) = (int8_t)(hq >> 2);       \
            *(int8_t*)(hb0 + ((PP) ^ 1) * 2048 + addrWb[e]) = (int8_t)(hq & 3);        \
            if (e == 0) hl0_ = hq; else hl1_ = hq;                                     \
        }                                                                              \
        BAR();                                                                         \
    }

    for (int tl = 0; tl < cs; tl += 2) {
        int tn2 = (tl + 2 < cs) ? tl + 2 : 0;   // harmless wrap on last iter
        STEP(0, gcur, gnx, tl + 1)
        STEP(1, gnx, gcur, tn2)
    }
#undef STEP

    // save state for next chunk (final buffer parity is 0 since cs is even)
    *(uint32_t*)(hst + tid * 4) = *(const uint32_t*)(hb0 + tid * 4);
    cst[0] = c_[0]; cst[1] = c_[1];

    if (t0 + cs == 512) {   // head: out = quant(h_last @ w_lin^T + b_lin), exact int64
        long long s = (long long)hl0_ * (long long)wlv[0] + (long long)hl1_ * (long long)wlv[1];
        s += __shfl_xor(s, 4);
        s += __shfl_xor(s, 8);
        s += __shfl_xor(s, 16);
        s += __shfl_xor(s, 32);
        if (lane < 4) redl[w][lane] = s;
        __syncthreads();
        if (tid < 4) {
            long long tot = 0;
#pragma unroll
            for (int ww = 0; ww < 8; ++ww) tot += redl[ww][tid];
            tot += 256LL * (long long)((const int*)(ws + WS_BLIN))[0];
            long long q = ((tot + 127) + ((tot >> 8) & 1)) >> 8;
            q = q < -32768 ? -32768 : (q > 32767 ? 32767 : q);
            out[wb * 4 + tid] = (float)q * 0.00390625f;
        }
    }
}

// ---------------- host ----------------
extern "C" void kernel_launch(void* const* d_in, const int* in_sizes, int n_in,
                              void* d_out, int out_size, void* d_ws, size_t ws_size,
                              hipStream_t stream) {
    const float* x    = (const float*)d_in[0];
    const float* wih  = (const float*)d_in[1];
    const float* whh  = (const float*)d_in[2];
    const float* bih  = (const float*)d_in[3];
    const float* bhh  = (const float*)d_in[4];
    const float* wlin = (const float*)d_in[5];
    const float* blin = (const float*)d_in[6];
    float* out = (float*)d_out;
    uint8_t* ws = (uint8_t*)d_ws;

    prep_kernel<<<512, 512, 0, stream>>>(wih, whh, bih, bhh, wlin, blin, ws);

    int cs = 512;
    while ((size_t)WS_GI + (size_t)cs * 524288u > ws_size && cs > 8) cs >>= 1;

    for (int t0 = 0; t0 < 512; t0 += cs) {
        gi_kernel<<<dim3(16, cs), 512, 0, stream>>>(x, ws, t0);
        recur_kernel<<<64, 512, 0, stream>>>(ws, out, t0, cs);
    }
}

// Round 5
// 596.420 us; speedup vs baseline: 3.4240x; 1.1594x over previous
//
#include <hip/hip_runtime.h>
#include <stdint.h>
#include <stddef.h>

typedef int i32x4 __attribute__((ext_vector_type(4)));
typedef int i32x2 __attribute__((ext_vector_type(2)));

// ---------------- workspace layout (bytes) ----------------
#define WS_WFRAG   0u          // 262144  w_hh int8, [w8][t8][ks4][lane64][16]
#define WS_WIH     262144u     // 131072  w_ih int8 [1024][128]
#define WS_BIASHH  393216u     // 4096    b_hh_int*256 as i32 [1024]
#define WS_BIASIH  397312u     // 4096    b_ih_int*256 as i32 [1024]
#define WS_WLIN    401408u     // 1024    w_lin int i32 [256]
#define WS_BLIN    402432u     // 4       b_lin int
#define WS_HSTATE  409600u     // 128 wg * 1024 = 131072 (h planes, swizzled)
#define WS_CSTATE  540672u     // 128*512*4 = 262144 (c per lane, 1 each)
#define WS_GI      1048576u    // cs * 524288 bytes (chunk-local step ring)

#define MFMA_I8(a,b,c) __builtin_amdgcn_mfma_i32_16x16x64_i8(a,b,c,0,0,0)
#define RHE8(x) ((((x) + 127) + (((x) >> 8) & 1)) >> 8)

// LDS-drain-only barrier: keeps global prefetch loads in flight across steps.
#define BAR() do { asm volatile("s_waitcnt lgkmcnt(0)" ::: "memory"); \
                   __builtin_amdgcn_s_barrier(); } while (0)

__device__ __forceinline__ float clamp3(float x, float lo, float hi) {
    return __builtin_amdgcn_fmed3f(x, lo, hi);
}
__device__ __forceinline__ float q16f(float x) {
    return clamp3(__builtin_rintf(x * 256.0f), -32768.0f, 32767.0f);
}
__device__ __forceinline__ int iclamp(int v, int lo, int hi) {
    return v < lo ? lo : (v > hi ? hi : v);
}

// ---------------- prep: quantize weights into fragment layouts ----------------
__global__ void prep_kernel(const float* __restrict__ wih, const float* __restrict__ whh,
                            const float* __restrict__ bih, const float* __restrict__ bhh,
                            const float* __restrict__ wlin, const float* __restrict__ blin,
                            uint8_t* __restrict__ ws) {
    int tid = blockIdx.x * blockDim.x + threadIdx.x;   // 262144 threads
    {   // w_hh -> A-fragment order: [w][t8][ks][lane][16B]
        int p = tid;
        int j = p & 15, lane = (p >> 4) & 63, ks = (p >> 10) & 3, t8 = (p >> 12) & 7, w = (p >> 15) & 7;
        int row = (t8 >> 1) * 256 + w * 32 + (t8 & 1) * 16 + (lane & 15);
        int k = ks * 64 + (lane >> 4) * 16 + j;
        int v = (int)q16f(whh[row * 256 + k]);
        v = iclamp(v, -127, 127);
        ((int8_t*)(ws + WS_WFRAG))[p] = (int8_t)v;
    }
    if (tid < 131072) {  // w_ih plain [gcol][k] int8
        int gcol = tid >> 7, k = tid & 127;
        int v = (int)q16f(wih[gcol * 128 + k]);
        v = iclamp(v, -127, 127);
        ((int8_t*)(ws + WS_WIH))[tid] = (int8_t)v;
    }
    if (tid < 1024) {    // biases scaled to 2^-16 units (i32)
        ((int*)(ws + WS_BIASHH))[tid] = ((int)q16f(bhh[tid])) * 256;
        ((int*)(ws + WS_BIASIH))[tid] = ((int)q16f(bih[tid])) * 256;
    }
    if (tid < 256) ((int*)(ws + WS_WLIN))[tid] = (int)q16f(wlin[tid]);
    if (tid == 0)  ((int*)(ws + WS_BLIN))[0]   = (int)q16f(blin[0]);
}

// ---------------- gi = quant(xq @ w_ih_q^T + b_ih_q), stored per-lane slot order ----------
__launch_bounds__(512, 2)
__global__ void gi_kernel(const float* __restrict__ x, uint8_t* __restrict__ ws, int t0) {
    __shared__ uint8_t xa[2048], xb[2048];   // x hi/lo i8 planes [16 rows][128 k], swizzled
    int tid = threadIdx.x;
    int wgr = blockIdx.x;          // batch group of 16, 0..15
    int tl  = blockIdx.y;          // chunk-local step  (ring index!)
    int t   = t0 + tl;             // global step (x read only)
    {   // stage + quantize + split x (x = 128a + b)
        int row = tid >> 5, c4 = (tid & 31) * 4;
        int b = wgr * 16 + row;
        const float4 xv = *(const float4*)(x + ((size_t)b * 512 + t) * 128 + c4);
        int v0 = (int)q16f(xv.x), v1 = (int)q16f(xv.y), v2 = (int)q16f(xv.z), v3 = (int)q16f(xv.w);
        uint32_t da = ((uint32_t)((v0 >> 7) & 255)) | ((uint32_t)((v1 >> 7) & 255) << 8) |
                      ((uint32_t)((v2 >> 7) & 255) << 16) | ((uint32_t)((v3 >> 7) & 255) << 24);
        uint32_t db = ((uint32_t)(v0 & 127)) | ((uint32_t)(v1 & 127) << 8) |
                      ((uint32_t)(v2 & 127) << 16) | ((uint32_t)(v3 & 127) << 24);
        int addr = row * 128 + (((c4 >> 4) ^ (row & 7)) * 16) + (c4 & 15);
        *(uint32_t*)(xa + addr) = da;
        *(uint32_t*)(xb + addr) = db;
    }
    __syncthreads();
    int wid = tid >> 6, lane = tid & 63, lr = lane & 15, lg = lane >> 4;
    const uint8_t* wq = ws + WS_WIH;
    i32x4 af[8][2];
#pragma unroll
    for (int mt = 0; mt < 8; ++mt) {
        int gcol = (mt >> 1) * 256 + wid * 32 + (mt & 1) * 16 + lr;
#pragma unroll
        for (int kt = 0; kt < 2; ++kt)
            af[mt][kt] = *(const i32x4*)(wq + gcol * 128 + kt * 64 + lg * 16);
    }
    i32x4 bha[2], bhb[2];
#pragma unroll
    for (int kt = 0; kt < 2; ++kt) {
        int addr = lr * 128 + ((((kt * 4) + lg) ^ (lr & 7)) * 16);
        bha[kt] = *(const i32x4*)(xa + addr);
        bhb[kt] = *(const i32x4*)(xb + addr);
    }
    i32x4 acch[8], accl[8];
    const int* bi = (const int*)(ws + WS_BIASIH);
#pragma unroll
    for (int mt = 0; mt < 8; ++mt) {
        i32x4 z = {0, 0, 0, 0};
        int gb = (mt >> 1) * 256 + wid * 32 + (mt & 1) * 16 + lg * 4;
        i32x4 bc = *(const i32x4*)(bi + gb);
        acch[mt] = MFMA_I8(af[mt][0], bha[0], z);
        accl[mt] = MFMA_I8(af[mt][0], bhb[0], bc);   // bias folded into C (enters v once)
        acch[mt] = MFMA_I8(af[mt][1], bha[1], acch[mt]);
        accl[mt] = MFMA_I8(af[mt][1], bhb[1], accl[mt]);
    }
    // quantize (exact RHE) and scatter into recur's per-lane slot order
    int gq[8][4];
#pragma unroll
    for (int mt = 0; mt < 8; ++mt)
#pragma unroll
        for (int rr = 0; rr < 4; ++rr) {
            int v = acch[mt][rr] * 128 + accl[mt][rr];
            gq[mt][rr] = iclamp(RHE8(v), -32768, 32767);
        }
    // dest: wb = B>>1, w = wid, lane_d = (rr&1) | ((B&1)<<1) | (mm<<2) | ((rr>>1)<<3) | (lg<<4)
    unsigned wb = (unsigned)(wgr * 8 + (lr >> 1));
#pragma unroll
    for (int mm2 = 0; mm2 < 2; ++mm2)
#pragma unroll
        for (int rr2 = 0; rr2 < 4; ++rr2) {
            i32x2 outv;
            outv[0] = (gq[mm2][rr2] & 0xFFFF)     | (gq[2 + mm2][rr2] << 16);
            outv[1] = (gq[4 + mm2][rr2] & 0xFFFF) | (gq[6 + mm2][rr2] << 16);
            int lane_d = (rr2 & 1) | ((lr & 1) << 1) | (mm2 << 2) | ((rr2 >> 1) << 3) | (lg << 4);
            *(i32x2*)(ws + WS_GI + (size_t)tl * 524288u +
                      (size_t)((wb * 8u + (unsigned)wid) * 64u + (unsigned)lane_d) * 8u) = outv;
        }
}

// ---------------- recurrence: 128 WGs x 2 batch rows, W_hh resident in VGPRs --------------
// lane bits: 0=cp(plane), 1=cb(batch), 2=mm(tile parity), 3=X(k bit1), 4-5=sg
// per lane: k = w*32 + mm*16 + sg*4 + 2X + cp ; gates G=0..3 of (cb, k); 1 h-unit
__launch_bounds__(512, 2)
__global__ void recur_kernel(uint8_t* __restrict__ ws, float* __restrict__ out, int t0, int cs) {
    __shared__ __align__(16) uint8_t hbuf[2][1024];   // [dbuf][b(2)][p(2)][256 k] swizzled
    __shared__ unsigned short lut[1544];              // quant(hard_sigmoid) LUT, u in [0,1536]
    __shared__ long long redl[8][2];
    int tid = threadIdx.x, w = tid >> 6, lane = tid & 63;
    int wb = blockIdx.x;
    int cp = lane & 1;
    int cb = (lane >> 1) & 1;
    int mm = (lane >> 2) & 1;
    int X  = (lane >> 3) & 1;
    int sg = lane >> 4;
    uint8_t* hb0 = &hbuf[0][0];

    // sigmoid LUT built with the EXACT fp64 expression the np reference evaluates
    for (int u = tid; u < 1537; u += 512) {
        double y = ((double)(u - 768) / 256.0) / 6.0 + 0.5;
        y = y < 0.0 ? 0.0 : (y > 1.0 ? 1.0 : y);
        lut[u] = (unsigned short)(int)__builtin_rint(y * 256.0);
    }

    // W_hh fragments -> registers (persistent across all steps)
    i32x4 wf[8][4];
#pragma unroll
    for (int t8 = 0; t8 < 8; ++t8)
#pragma unroll
        for (int ks = 0; ks < 4; ++ks)
            wf[t8][ks] = *(const i32x4*)(ws + WS_WFRAG + (((unsigned)(w * 8 + t8) * 4 + ks) << 10) + lane * 16);

    // static per-lane addresses
    int addrB[4];
#pragma unroll
    for (int ks = 0; ks < 4; ++ks)
        addrB[ks] = (cb * 2 + cp) * 256 + ((ks * 64 + sg * 16) ^ (cp << 6) ^ (cb << 5));

    int k_own = w * 32 + mm * 16 + sg * 4 + 2 * X + cp;
    int addrWa = cb * 512 + (k_own ^ (cb << 5));
    int addrWb = cb * 512 + 256 + (k_own ^ 64 ^ (cb << 5));
    int biasP[4], wlv;
    {
        const int* bhh256 = (const int*)(ws + WS_BIASHH);
#pragma unroll
        for (int G = 0; G < 4; ++G)
            biasP[G] = bhh256[G * 256 + k_own] + (G == 2 ? 0 : 768 * 256);  // sigmoid pre-bias
        wlv = ((const int*)(ws + WS_WLIN))[k_own];
    }
    size_t gioff = (size_t)((unsigned)wb * 8u + (unsigned)w) * 512u + (unsigned)lane * 8u;

    uint8_t* hst = ws + WS_HSTATE + (unsigned)wb * 1024u;
    int* cst = (int*)(ws + WS_CSTATE) + (unsigned)wb * 512u + (unsigned)tid;

    int c_;
    if (t0 == 0) {
        c_ = 0;
        if (tid < 256) *(uint32_t*)(hb0 + tid * 4) = 0u;
    } else {
        c_ = *cst;
        if (tid < 256) *(uint32_t*)(hb0 + tid * 4) = *(const uint32_t*)(hst + tid * 4);
    }
    // prefetch gi for step 0 (stays in VGPRs across the barrier)
    i32x2 gcur = *(const i32x2*)(ws + WS_GI + gioff);
    i32x2 gnx;
    __syncthreads();

    int hl_ = 0;
    const i32x4 zerov = {0, 0, 0, 0};

    // Per slot G: own acc reg r = 2X+cp of tile t8=2G+mm; partner (lane^1) supplies
    // the other plane's value at the same r via one ds_swizzle (sends r = 2X+(1-cp)).
#define GIV(GUSE, G) ((G & 1) ? (GUSE[G >> 1] >> 16) : ((GUSE[G >> 1] << 16) >> 16))
#define SLOT(G, OUTV)                                                                  \
    {                                                                                  \
        int u0 = X ? acc[2 * G][2]     : acc[2 * G][0];                                \
        int u1 = X ? acc[2 * G][3]     : acc[2 * G][1];                                \
        int v0 = X ? acc[2 * G + 1][2] : acc[2 * G + 1][0];                            \
        int v1 = X ? acc[2 * G + 1][3] : acc[2 * G + 1][1];                            \
        int w0 = mm ? v0 : u0;                                                         \
        int w1 = mm ? v1 : u1;                                                         \
        int own = cp ? w1 : w0;                                                        \
        int snd = cp ? w0 : w1;                                                        \
        int z = __builtin_amdgcn_ds_swizzle(snd, 0x41F);                               \
        int d = cp ? ((z << 2) + own) : ((own << 2) + z);                              \
        OUTV = RHE8(d + biasP[G]);                                                     \
    }
#define STEP(PP, GUSE, GPRE, TPRE)                                                     \
    {                                                                                  \
        GPRE = *(const i32x2*)(ws + WS_GI + (size_t)(TPRE) * 524288u + gioff);         \
        i32x4 acc[8];                                                                  \
        _Pragma("unroll")                                                              \
        for (int ks = 0; ks < 4; ++ks) {                                               \
            i32x4 bf = *(const i32x4*)(hb0 + (PP) * 1024 + addrB[ks]);                 \
            _Pragma("unroll")                                                          \
            for (int t8 = 0; t8 < 8; ++t8)                                             \
                acc[t8] = (ks == 0) ? MFMA_I8(wf[t8][0], bf, zerov)                    \
                                    : MFMA_I8(wf[t8][ks], bf, acc[t8]);                \
        }                                                                              \
        int g0, g1, g2, g3;                                                            \
        SLOT(0, g0) SLOT(1, g1) SLOT(2, g2) SLOT(3, g3)                                \
        int gate0 = (int)lut[iclamp(g0 + GIV(GUSE, 0), 0, 1536)];                      \
        int gate1 = (int)lut[iclamp(g1 + GIV(GUSE, 1), 0, 1536)];                      \
        int gate2 = iclamp(g2 + GIV(GUSE, 2), -256, 256);                              \
        int gate3 = (int)lut[iclamp(g3 + GIV(GUSE, 3), 0, 1536)];                      \
        int fcq = RHE8(__mul24(gate1, c_));                                            \
        int icq = RHE8(__mul24(gate0, gate2));                                         \
        int cn  = iclamp(fcq + icq, -32768, 32767);                                    \
        c_ = cn;                                                                       \
        int th = iclamp(cn, -256, 256);                                                \
        int hq = RHE8(__mul24(gate3, th));                                             \
        *(int8_t*)(hb0 + ((PP) ^ 1) * 1024 + addrWa) = (int8_t)(hq >> 2);              \
        *(int8_t*)(hb0 + ((PP) ^ 1) * 1024 + addrWb) = (int8_t)(hq & 3);               \
        hl_ = hq;                                                                      \
        BAR();                                                                         \
    }

    for (int tl = 0; tl < cs; tl += 2) {
        int tn2 = (tl + 2 < cs) ? tl + 2 : 0;   // harmless wrap on last iter
        STEP(0, gcur, gnx, tl + 1)
        STEP(1, gnx, gcur, tn2)
    }
#undef STEP
#undef SLOT
#undef GIV

    // save state for next chunk (final buffer parity is 0 since cs is even)
    if (tid < 256) *(uint32_t*)(hst + tid * 4) = *(const uint32_t*)(hb0 + tid * 4);
    *cst = c_;

    if (t0 + cs == 512) {   // head: out = quant(h_last @ w_lin^T + b_lin), exact int64
        long long s = (long long)hl_ * (long long)wlv;
        s += __shfl_xor(s, 1);
        s += __shfl_xor(s, 4);
        s += __shfl_xor(s, 8);
        s += __shfl_xor(s, 16);
        s += __shfl_xor(s, 32);
        if ((lane & 61) == 0) redl[w][cb] = s;   // lanes 0 and 2
        __syncthreads();
        if (tid < 2) {
            long long tot = 0;
#pragma unroll
            for (int ww = 0; ww < 8; ++ww) tot += redl[ww][tid];
            tot += 256LL * (long long)((const int*)(ws + WS_BLIN))[0];
            long long q = ((tot + 127) + ((tot >> 8) & 1)) >> 8;
            q = q < -32768 ? -32768 : (q > 32767 ? 32767 : q);
            out[wb * 2 + tid] = (float)q * 0.00390625f;
        }
    }
}

// ---------------- host ----------------
extern "C" void kernel_launch(void* const* d_in, const int* in_sizes, int n_in,
                              void* d_out, int out_size, void* d_ws, size_t ws_size,
                              hipStream_t stream) {
    const float* x    = (const float*)d_in[0];
    const float* wih  = (const float*)d_in[1];
    const float* whh  = (const float*)d_in[2];
    const float* bih  = (const float*)d_in[3];
    const float* bhh  = (const float*)d_in[4];
    const float* wlin = (const float*)d_in[5];
    const float* blin = (const float*)d_in[6];
    float* out = (float*)d_out;
    uint8_t* ws = (uint8_t*)d_ws;

    prep_kernel<<<512, 512, 0, stream>>>(wih, whh, bih, bhh, wlin, blin, ws);

    int cs = 512;
    while ((size_t)WS_GI + (size_t)cs * 524288u > ws_size && cs > 8) cs >>= 1;

    for (int t0 = 0; t0 < 512; t0 += cs) {
        gi_kernel<<<dim3(16, cs), 512, 0, stream>>>(x, ws, t0);
        recur_kernel<<<128, 512, 0, stream>>>(ws, out, t0, cs);
    }
}